// Round 1
// baseline (590.854 us; speedup 1.0000x reference)
//
#include <hip/hip_runtime.h>
#include <math.h>

#define LSEQ 512
#define DG 256
#define DB 128
#define NH 8
#define HD 32
#define EPSV 1e-5f

// ---------------------------------------------------------------------------
// Kernel 1: layernorm(x) + Q/K/V/Gate projections.
// grid 256 blocks x 256 threads; each block handles 4 rows (one per wave) to
// amortize the 1 MB of weight reads across rows (256 MB total from L2).
// ---------------------------------------------------------------------------
__global__ __launch_bounds__(256) void prep_kernel(
    const float* __restrict__ x, const float* __restrict__ g_gamma,
    const float* __restrict__ g_beta, const float* __restrict__ Wq,
    const float* __restrict__ Wk, const float* __restrict__ Wv,
    const float* __restrict__ Wg, const float* __restrict__ bg,
    float* __restrict__ q_ws, float* __restrict__ k_ws,
    float* __restrict__ v_ws, float* __restrict__ g_ws)
{
    __shared__ float xs[4][DG];
    const int t = threadIdx.x;
    const int wave = t >> 6, lane = t & 63;
    const int row0 = blockIdx.x << 2;

    // one wave per row: layernorm over 256 (64 lanes x float4)
    {
        const int row = row0 + wave;
        const float4 xv = *(const float4*)(x + (size_t)row * DG + lane * 4);
        float s  = xv.x + xv.y + xv.z + xv.w;
        float ss = xv.x*xv.x + xv.y*xv.y + xv.z*xv.z + xv.w*xv.w;
        #pragma unroll
        for (int m = 32; m >= 1; m >>= 1) { s += __shfl_xor(s, m); ss += __shfl_xor(ss, m); }
        const float mean = s * (1.f / DG);
        const float rstd = rsqrtf(ss * (1.f / DG) - mean * mean + EPSV);
        const float4 gg = *(const float4*)(g_gamma + lane * 4);
        const float4 gb = *(const float4*)(g_beta + lane * 4);
        float4 xo;
        xo.x = (xv.x - mean) * rstd * gg.x + gb.x;
        xo.y = (xv.y - mean) * rstd * gg.y + gb.y;
        xo.z = (xv.z - mean) * rstd * gg.z + gb.z;
        xo.w = (xv.w - mean) * rstd * gg.w + gb.w;
        *(float4*)&xs[wave][lane * 4] = xo;
    }
    __syncthreads();

    float aq[4] = {0,0,0,0}, ak[4] = {0,0,0,0}, av[4] = {0,0,0,0}, ag[4] = {0,0,0,0};
    #pragma unroll 4
    for (int c = 0; c < DG; ++c) {
        const float wq = Wq[(size_t)c * DG + t];
        const float wk = Wk[(size_t)c * DG + t];
        const float wv = Wv[(size_t)c * DG + t];
        const float wg = Wg[(size_t)c * DG + t];
        #pragma unroll
        for (int r = 0; r < 4; ++r) {
            const float xr = xs[r][c];
            aq[r] = fmaf(xr, wq, aq[r]);
            ak[r] = fmaf(xr, wk, ak[r]);
            av[r] = fmaf(xr, wv, av[r]);
            ag[r] = fmaf(xr, wg, ag[r]);
        }
    }

    const float scal = 0.17677669529663687f;  // 1/sqrt(32)
    const float bgv = bg[t];
    #pragma unroll
    for (int r = 0; r < 4; ++r) {
        const size_t o = (size_t)(row0 + r) * DG + t;
        q_ws[o] = aq[r];
        k_ws[o] = ak[r] * scal;          // fold 1/sqrt(D) into k
        v_ws[o] = av[r];
        g_ws[o] = 1.f / (1.f + __expf(-(ag[r] + bgv)));  // sigmoid gate
    }
}

// ---------------------------------------------------------------------------
// Kernel 2: fused  bias-layernorm -> pair_b -> +qk -> softmax(k) -> @v ->
//           gate -> @Wout + bout.   One block per (b, q): 1024 blocks x 256.
// bias slice per block: 512 rows x 128 floats = 256 KB streamed (the HBM
// bottleneck). pair_b never touches memory.
// ---------------------------------------------------------------------------
__global__ __launch_bounds__(256) void attn_kernel(
    const float* __restrict__ bias, const float* __restrict__ b_gamma,
    const float* __restrict__ b_beta, const float* __restrict__ Wb,
    const float* __restrict__ Wout, const float* __restrict__ bout,
    const float* __restrict__ q_ws, const float* __restrict__ k_ws,
    const float* __restrict__ v_ws, const float* __restrict__ g_ws,
    float* __restrict__ out)
{
    __shared__ float logit[LSEQ * NH];   // 16 KB, [k][h]
    __shared__ float q_sp[NH * 33];      // padded to kill bank conflicts
    __shared__ float s1_s[NH], s0_s[NH], rden_s[NH];
    __shared__ float row_s[DG];

    const int t = threadIdx.x;
    const int bq = blockIdx.x;           // b*512 + q
    const int b = bq >> 9;

    // ---- staging ----
    q_sp[(t >> 5) * 33 + (t & 31)] = q_ws[(size_t)bq * DG + t];
    if (t < NH) {  // S1[h] = sum_c gamma_c*Wb[c][h], S0[h] = sum_c beta_c*Wb[c][h]
        float s1 = 0.f, s0 = 0.f;
        for (int c = 0; c < DB; ++c) {
            const float w = Wb[(size_t)c * NH + t];
            s1 = fmaf(b_gamma[c], w, s1);
            s0 = fmaf(b_beta[c],  w, s0);
        }
        s1_s[t] = s1; s0_s[t] = s0;
    }
    __syncthreads();

    // ---- Phase A2: logit[k][h] = q[h,:] . k_scaled[k,h,:] ----
    {
        const int h = t & 7, kk = t >> 3;
        const float* qrow = &q_sp[h * 33];
        for (int it = 0; it < 16; ++it) {
            const int k = it * 32 + kk;
            const float* kv = k_ws + ((size_t)(b * LSEQ + k)) * DG + h * HD;
            float acc = 0.f;
            #pragma unroll
            for (int d4 = 0; d4 < 8; ++d4) {
                const float4 kvv = *(const float4*)(kv + d4 * 4);
                acc = fmaf(qrow[d4*4+0], kvv.x, acc);
                acc = fmaf(qrow[d4*4+1], kvv.y, acc);
                acc = fmaf(qrow[d4*4+2], kvv.z, acc);
                acc = fmaf(qrow[d4*4+3], kvv.w, acc);
            }
            logit[k * NH + h] = acc;
        }
    }
    __syncthreads();

    // ---- Phase A1: bias layernorm + Wb  ->  logit += pair_b ----
    // 32 lanes per bias row (coalesced float4/lane); layernorm algebra:
    // p[h] = rstd*(dot_h - mean*S1[h]) + S0[h],  dot_h = sum_c bv_c*gamma_c*Wb[c][h]
    {
        const int g = t >> 5, lane = t & 31;
        const int c0 = lane * 4;
        const int bit4 = (lane >> 4) & 1, bit3 = (lane >> 3) & 1, bit2 = (lane >> 2) & 1;
        const int h_mine = bit4 * 4 + bit3 * 2 + bit2;
        const bool writer = (lane & 3) == 0;
        const float s1m = s1_s[h_mine], s0m = s0_s[h_mine];

        // per-lane gamma*Wb block held in registers (c range fixed per lane)
        const float4 gm4 = *(const float4*)(b_gamma + c0);
        const float gam[4] = {gm4.x, gm4.y, gm4.z, gm4.w};
        float gw[4][8];
        #pragma unroll
        for (int j = 0; j < 4; ++j) {
            const float4 wa = *(const float4*)(Wb + (size_t)(c0 + j) * NH);
            const float4 wb2 = *(const float4*)(Wb + (size_t)(c0 + j) * NH + 4);
            gw[j][0] = gam[j]*wa.x;  gw[j][1] = gam[j]*wa.y;
            gw[j][2] = gam[j]*wa.z;  gw[j][3] = gam[j]*wa.w;
            gw[j][4] = gam[j]*wb2.x; gw[j][5] = gam[j]*wb2.y;
            gw[j][6] = gam[j]*wb2.z; gw[j][7] = gam[j]*wb2.w;
        }

        const float* brow_base = bias + (size_t)bq * LSEQ * DB;
        for (int it = 0; it < 64; ++it) {
            const int k = it * 8 + g;
            const float4 bv = *(const float4*)(brow_base + (size_t)k * DB + c0);
            float s  = bv.x + bv.y + bv.z + bv.w;
            float ss = fmaf(bv.x, bv.x, fmaf(bv.y, bv.y, fmaf(bv.z, bv.z, bv.w * bv.w)));
            #pragma unroll
            for (int m = 16; m >= 1; m >>= 1) { s += __shfl_xor(s, m); ss += __shfl_xor(ss, m); }
            const float mean = s * (1.f / DB);
            const float rstd = rsqrtf(ss * (1.f / DB) - mean * mean + EPSV);

            float dot[8];
            #pragma unroll
            for (int h = 0; h < 8; ++h)
                dot[h] = fmaf(bv.x, gw[0][h], fmaf(bv.y, gw[1][h],
                         fmaf(bv.z, gw[2][h], bv.w * gw[3][h])));

            // select-halving reduction: 8 values over 32 lanes -> h-distributed
            float m4[4];
            #pragma unroll
            for (int j = 0; j < 4; ++j) {
                const float keep = bit4 ? dot[4 + j] : dot[j];
                const float send = bit4 ? dot[j] : dot[4 + j];
                m4[j] = keep + __shfl_xor(send, 16);
            }
            float m2[2];
            #pragma unroll
            for (int j = 0; j < 2; ++j) {
                const float keep = bit3 ? m4[2 + j] : m4[j];
                const float send = bit3 ? m4[j] : m4[2 + j];
                m2[j] = keep + __shfl_xor(send, 8);
            }
            float m1;
            {
                const float keep = bit2 ? m2[1] : m2[0];
                const float send = bit2 ? m2[0] : m2[1];
                m1 = keep + __shfl_xor(send, 4);
            }
            m1 += __shfl_xor(m1, 2);
            m1 += __shfl_xor(m1, 1);

            if (writer)
                logit[k * NH + h_mine] += rstd * (m1 - mean * s1m) + s0m;
        }
    }
    __syncthreads();

    // ---- Phase B: softmax over k, per h ----
    {
        const int h = t >> 5, lane = t & 31;
        float mx = -1e30f;
        for (int j = 0; j < 16; ++j) mx = fmaxf(mx, logit[(lane + j * 32) * NH + h]);
        #pragma unroll
        for (int m = 16; m >= 1; m >>= 1) mx = fmaxf(mx, __shfl_xor(mx, m));
        float s = 0.f;
        for (int j = 0; j < 16; ++j) {
            const int idx = (lane + j * 32) * NH + h;
            const float e = __expf(logit[idx] - mx);
            logit[idx] = e;
            s += e;
        }
        #pragma unroll
        for (int m = 16; m >= 1; m >>= 1) s += __shfl_xor(s, m);
        if (lane == 0) rden_s[h] = 1.f / s;
    }
    __syncthreads();

    // ---- Phase C: out[h,d] = sum_k attn[k,h]*v[k,h,d]; gate ----
    {
        const int h = t >> 5;                 // t == h*32 + d
        float acc = 0.f;
        const float* vb = v_ws + (size_t)(b * LSEQ) * DG + t;
        #pragma unroll 8
        for (int k = 0; k < LSEQ; ++k)
            acc = fmaf(logit[k * NH + h], vb[(size_t)k * DG], acc);
        row_s[t] = acc * rden_s[h] * g_ws[(size_t)bq * DG + t];
    }
    __syncthreads();

    // ---- Phase D: row @ Wout + bout ----
    {
        float o = bout[t];
        #pragma unroll 4
        for (int c = 0; c < DG; ++c)
            o = fmaf(row_s[c], Wout[(size_t)c * DG + t], o);
        out[(size_t)bq * DG + t] = o;
    }
}

extern "C" void kernel_launch(void* const* d_in, const int* in_sizes, int n_in,
                              void* d_out, int out_size, void* d_ws, size_t ws_size,
                              hipStream_t stream)
{
    const float* x       = (const float*)d_in[0];
    const float* bias    = (const float*)d_in[1];
    const float* g_gamma = (const float*)d_in[2];
    const float* g_beta  = (const float*)d_in[3];
    const float* b_gamma = (const float*)d_in[4];
    const float* b_beta  = (const float*)d_in[5];
    const float* Wq      = (const float*)d_in[6];
    const float* Wk      = (const float*)d_in[7];
    const float* Wv      = (const float*)d_in[8];
    const float* Wb      = (const float*)d_in[9];
    const float* Wg      = (const float*)d_in[10];
    const float* bg      = (const float*)d_in[11];
    const float* Wout    = (const float*)d_in[12];
    const float* bout    = (const float*)d_in[13];
    float* out = (float*)d_out;

    float* ws   = (float*)d_ws;
    float* q_ws = ws;                 // [1024, 256] each = 1 MB
    float* k_ws = ws + 262144;
    float* v_ws = ws + 2 * 262144;
    float* g_ws = ws + 3 * 262144;

    hipLaunchKernelGGL(prep_kernel, dim3(256), dim3(256), 0, stream,
                       x, g_gamma, g_beta, Wq, Wk, Wv, Wg, bg,
                       q_ws, k_ws, v_ws, g_ws);
    hipLaunchKernelGGL(attn_kernel, dim3(1024), dim3(256), 0, stream,
                       bias, b_gamma, b_beta, Wb, Wout, bout,
                       q_ws, k_ws, v_ws, g_ws, out);
}

// Round 2
// 561.512 us; speedup vs baseline: 1.0523x; 1.0523x over previous
//
#include <hip/hip_runtime.h>
#include <math.h>

#define LSEQ 512
#define DG 256
#define DB 128
#define NH 8
#define HD 32
#define LP 520          // logit LDS row stride [h][LP] -> conflict-free softmax
#define EPSV 1e-5f

// ---------------------------------------------------------------------------
// Kernel 1: layernorm(x) + Q/K/V/Gate projections.
// 512 blocks x 256 threads, 2 rows per block (2 blocks/CU, unroll-8 ILP).
// ---------------------------------------------------------------------------
__global__ __launch_bounds__(256) void prep_kernel(
    const float* __restrict__ x, const float* __restrict__ g_gamma,
    const float* __restrict__ g_beta, const float* __restrict__ Wq,
    const float* __restrict__ Wk, const float* __restrict__ Wv,
    const float* __restrict__ Wg, const float* __restrict__ bg,
    float* __restrict__ q_ws, float* __restrict__ k_ws,
    float* __restrict__ v_ws, float* __restrict__ g_ws)
{
    __shared__ float xs[2][DG];
    const int t = threadIdx.x;
    const int wave = t >> 6, lane = t & 63;
    const int row0 = blockIdx.x << 1;

    if (wave < 2) {  // one wave per row: layernorm over 256 (64 lanes x float4)
        const int row = row0 + wave;
        const float4 xv = *(const float4*)(x + (size_t)row * DG + lane * 4);
        float s  = xv.x + xv.y + xv.z + xv.w;
        float ss = xv.x*xv.x + xv.y*xv.y + xv.z*xv.z + xv.w*xv.w;
        #pragma unroll
        for (int m = 32; m >= 1; m >>= 1) { s += __shfl_xor(s, m); ss += __shfl_xor(ss, m); }
        const float mean = s * (1.f / DG);
        const float rstd = rsqrtf(ss * (1.f / DG) - mean * mean + EPSV);
        const float4 gg = *(const float4*)(g_gamma + lane * 4);
        const float4 gb = *(const float4*)(g_beta + lane * 4);
        float4 xo;
        xo.x = (xv.x - mean) * rstd * gg.x + gb.x;
        xo.y = (xv.y - mean) * rstd * gg.y + gb.y;
        xo.z = (xv.z - mean) * rstd * gg.z + gb.z;
        xo.w = (xv.w - mean) * rstd * gg.w + gb.w;
        *(float4*)&xs[wave][lane * 4] = xo;
    }
    __syncthreads();

    float aq0=0, aq1=0, ak0=0, ak1=0, av0=0, av1=0, ag0=0, ag1=0;
    #pragma unroll 8
    for (int c = 0; c < DG; ++c) {
        const float wq = Wq[(size_t)c * DG + t];
        const float wk = Wk[(size_t)c * DG + t];
        const float wv = Wv[(size_t)c * DG + t];
        const float wg = Wg[(size_t)c * DG + t];
        const float x0 = xs[0][c], x1 = xs[1][c];
        aq0 = fmaf(x0, wq, aq0);  aq1 = fmaf(x1, wq, aq1);
        ak0 = fmaf(x0, wk, ak0);  ak1 = fmaf(x1, wk, ak1);
        av0 = fmaf(x0, wv, av0);  av1 = fmaf(x1, wv, av1);
        ag0 = fmaf(x0, wg, ag0);  ag1 = fmaf(x1, wg, ag1);
    }

    const float scal = 0.17677669529663687f;  // 1/sqrt(32)
    const float bgv = bg[t];
    {
        const size_t o0 = (size_t)row0 * DG + t;
        const size_t o1 = o0 + DG;
        q_ws[o0] = aq0;               q_ws[o1] = aq1;
        k_ws[o0] = ak0 * scal;        k_ws[o1] = ak1 * scal;   // fold 1/sqrt(D)
        v_ws[o0] = av0;               v_ws[o1] = av1;
        g_ws[o0] = 1.f / (1.f + __expf(-(ag0 + bgv)));
        g_ws[o1] = 1.f / (1.f + __expf(-(ag1 + bgv)));
    }
}

// ---------------------------------------------------------------------------
// Kernel 2: fused bias-LN -> pair_b ; qk ; softmax(k) ; @v ; gate ; @Wout.
// One block per (b,q): 1024 blocks x 1024 threads (16 waves for TLP).
// ---------------------------------------------------------------------------
__global__ __launch_bounds__(1024) void attn_kernel(
    const float* __restrict__ bias, const float* __restrict__ b_gamma,
    const float* __restrict__ b_beta, const float* __restrict__ Wb,
    const float* __restrict__ Wout, const float* __restrict__ bout,
    const float* __restrict__ q_ws, const float* __restrict__ k_ws,
    const float* __restrict__ v_ws, const float* __restrict__ g_ws,
    float* __restrict__ out)
{
    __shared__ float lg[NH * LP];     // qk logits, transposed [h][k]
    __shared__ float pb[NH * LP];     // pair bias,  transposed [h][k]
    __shared__ float q_sp[NH * 33];   // q row, padded
    __shared__ float s1_s[NH], s0_s[NH], rden_s[NH];
    __shared__ float ps[4][DG];       // phase C/D partials
    __shared__ float row_s[DG];

    const int t = threadIdx.x;
    const int bq = blockIdx.x;        // b*512 + q
    const int b = bq >> 9;

    // ---- staging (pre-sync) ----
    if (t < DG) {                      // q row into padded LDS
        q_sp[(t >> 5) * 33 + (t & 31)] = q_ws[(size_t)bq * DG + t];
    } else if (t < 2 * DG) {           // S1[h], S0[h] by waves 4-7 (parallel)
        const int tt = t - DG;
        const int h = tt >> 5, l = tt & 31, c0 = l * 4;
        float s1 = 0.f, s0 = 0.f;
        #pragma unroll
        for (int j = 0; j < 4; ++j) {
            const float w = Wb[(size_t)(c0 + j) * NH + h];
            s1 = fmaf(b_gamma[c0 + j], w, s1);
            s0 = fmaf(b_beta[c0 + j],  w, s0);
        }
        #pragma unroll
        for (int m = 16; m >= 1; m >>= 1) { s1 += __shfl_xor(s1, m); s0 += __shfl_xor(s0, m); }
        if (l == 0) { s1_s[h] = s1; s0_s[h] = s0; }
    }
    __syncthreads();

    // ---- Phase A2: lg[h][k] = q[h,:] . k_scaled[k,h,:]  (4 dots/thread) ----
    {
        const int h = t & 7, kk = t >> 3;     // kk in [0,128)
        const float* qrow = &q_sp[h * 33];
        const float* kbase = k_ws + (size_t)(b * LSEQ) * DG + h * HD;
        #pragma unroll
        for (int j = 0; j < 4; ++j) {
            const int k = kk + j * 128;
            const float* kv = kbase + (size_t)k * DG;
            float acc = 0.f;
            #pragma unroll
            for (int d4 = 0; d4 < 8; ++d4) {
                const float4 kvv = *(const float4*)(kv + d4 * 4);
                acc = fmaf(qrow[d4*4+0], kvv.x, acc);
                acc = fmaf(qrow[d4*4+1], kvv.y, acc);
                acc = fmaf(qrow[d4*4+2], kvv.z, acc);
                acc = fmaf(qrow[d4*4+3], kvv.w, acc);
            }
            lg[h * LP + k] = acc;
        }
    }

    // ---- Phase A1: bias layernorm + Wb -> pb[h][k] (32 groups x 16 rows,
    //      2 independent rows per iteration for ILP) ----
    {
        const int G = t >> 5, l = t & 31;
        const int c0 = l * 4;
        const int bit4 = (l >> 4) & 1, bit3 = (l >> 3) & 1, bit2 = (l >> 2) & 1;
        const int h_mine = bit4 * 4 + bit3 * 2 + bit2;
        const bool writer = (l & 3) == 0;
        const float s1m = s1_s[h_mine], s0m = s0_s[h_mine];

        const float4 gm4 = *(const float4*)(b_gamma + c0);
        const float gam[4] = {gm4.x, gm4.y, gm4.z, gm4.w};
        float gw[4][8];
        #pragma unroll
        for (int j = 0; j < 4; ++j) {
            const float4 wa = *(const float4*)(Wb + (size_t)(c0 + j) * NH);
            const float4 wb2 = *(const float4*)(Wb + (size_t)(c0 + j) * NH + 4);
            gw[j][0] = gam[j]*wa.x;  gw[j][1] = gam[j]*wa.y;
            gw[j][2] = gam[j]*wa.z;  gw[j][3] = gam[j]*wa.w;
            gw[j][4] = gam[j]*wb2.x; gw[j][5] = gam[j]*wb2.y;
            gw[j][6] = gam[j]*wb2.z; gw[j][7] = gam[j]*wb2.w;
        }

        const float* bb = bias + (size_t)bq * LSEQ * DB;
        for (int it = 0; it < 8; ++it) {
            const int ka = it * 32 + G;
            const int kb = ka + 256;
            const float4 va = *(const float4*)(bb + (size_t)ka * DB + c0);
            const float4 vb2 = *(const float4*)(bb + (size_t)kb * DB + c0);

            float sa  = va.x + va.y + va.z + va.w;
            float sb  = vb2.x + vb2.y + vb2.z + vb2.w;
            float ssa = fmaf(va.x, va.x, fmaf(va.y, va.y, fmaf(va.z, va.z, va.w * va.w)));
            float ssb = fmaf(vb2.x, vb2.x, fmaf(vb2.y, vb2.y, fmaf(vb2.z, vb2.z, vb2.w * vb2.w)));
            #pragma unroll
            for (int m = 16; m >= 1; m >>= 1) {
                sa += __shfl_xor(sa, m);   ssa += __shfl_xor(ssa, m);
                sb += __shfl_xor(sb, m);   ssb += __shfl_xor(ssb, m);
            }
            const float mean_a = sa * (1.f / DB);
            const float mean_b = sb * (1.f / DB);
            const float rstd_a = rsqrtf(ssa * (1.f / DB) - mean_a * mean_a + EPSV);
            const float rstd_b = rsqrtf(ssb * (1.f / DB) - mean_b * mean_b + EPSV);

            float da[8], db2[8];
            #pragma unroll
            for (int h = 0; h < 8; ++h) {
                da[h]  = fmaf(va.x, gw[0][h], fmaf(va.y, gw[1][h],
                         fmaf(va.z, gw[2][h], va.w * gw[3][h])));
                db2[h] = fmaf(vb2.x, gw[0][h], fmaf(vb2.y, gw[1][h],
                         fmaf(vb2.z, gw[2][h], vb2.w * gw[3][h])));
            }

            // select-halving reduce (both rows interleaved)
            float a4[4], b4[4];
            #pragma unroll
            for (int j = 0; j < 4; ++j) {
                float ka_ = bit4 ? da[4 + j] : da[j];
                float sa_ = bit4 ? da[j] : da[4 + j];
                a4[j] = ka_ + __shfl_xor(sa_, 16);
                float kb_ = bit4 ? db2[4 + j] : db2[j];
                float sb_ = bit4 ? db2[j] : db2[4 + j];
                b4[j] = kb_ + __shfl_xor(sb_, 16);
            }
            float a2[2], b2[2];
            #pragma unroll
            for (int j = 0; j < 2; ++j) {
                float ka_ = bit3 ? a4[2 + j] : a4[j];
                float sa_ = bit3 ? a4[j] : a4[2 + j];
                a2[j] = ka_ + __shfl_xor(sa_, 8);
                float kb_ = bit3 ? b4[2 + j] : b4[j];
                float sb_ = bit3 ? b4[j] : b4[2 + j];
                b2[j] = kb_ + __shfl_xor(sb_, 8);
            }
            float a1, b1;
            {
                float ka_ = bit2 ? a2[1] : a2[0];
                float sa_ = bit2 ? a2[0] : a2[1];
                a1 = ka_ + __shfl_xor(sa_, 4);
                float kb_ = bit2 ? b2[1] : b2[0];
                float sb_ = bit2 ? b2[0] : b2[1];
                b1 = kb_ + __shfl_xor(sb_, 4);
            }
            a1 += __shfl_xor(a1, 2);  b1 += __shfl_xor(b1, 2);
            a1 += __shfl_xor(a1, 1);  b1 += __shfl_xor(b1, 1);

            if (writer) {
                pb[h_mine * LP + ka] = rstd_a * (a1 - mean_a * s1m) + s0m;
                pb[h_mine * LP + kb] = rstd_b * (b1 - mean_b * s1m) + s0m;
            }
        }
    }
    __syncthreads();

    // ---- Phase B: softmax over k per h (threads 0..255; conflict-free) ----
    if (t < 256) {
        const int h = t >> 5, l = t & 31;
        float* lrow = &lg[h * LP];
        const float* prow = &pb[h * LP];
        float mx = -1e30f;
        #pragma unroll
        for (int j = 0; j < 16; ++j) {
            const int k = l + j * 32;
            const float v = lrow[k] + prow[k];
            lrow[k] = v;
            mx = fmaxf(mx, v);
        }
        #pragma unroll
        for (int m = 16; m >= 1; m >>= 1) mx = fmaxf(mx, __shfl_xor(mx, m));
        float s = 0.f;
        #pragma unroll
        for (int j = 0; j < 16; ++j) {
            const int k = l + j * 32;
            const float e = __expf(lrow[k] - mx);
            lrow[k] = e;
            s += e;
        }
        #pragma unroll
        for (int m = 16; m >= 1; m >>= 1) s += __shfl_xor(s, m);
        if (l == 0) rden_s[h] = 1.f / s;
    }
    __syncthreads();

    // ---- Phase C: out[c] = sum_k p[k,h]*v[k,c], k split 4-way ----
    {
        const int c = t & 255, kq = t >> 8;     // kq in [0,4)
        const int h = c >> 5;
        const float* vb = v_ws + ((size_t)(b * LSEQ) + kq * 128) * DG + c;
        const float* lgb = &lg[h * LP + kq * 128];
        float a0 = 0.f, a1 = 0.f;
        #pragma unroll 8
        for (int i = 0; i < 128; i += 2) {
            a0 = fmaf(lgb[i],     vb[(size_t)i * DG],       a0);
            a1 = fmaf(lgb[i + 1], vb[(size_t)(i + 1) * DG], a1);
        }
        ps[kq][c] = a0 + a1;
    }
    __syncthreads();
    if (t < DG) {
        const float s = (ps[0][t] + ps[1][t] + ps[2][t] + ps[3][t])
                        * rden_s[t >> 5] * g_ws[(size_t)bq * DG + t];
        row_s[t] = s;
    }
    __syncthreads();

    // ---- Phase D: out_row = row_s @ Wout + bout, c' split 4-way ----
    {
        const int c = t & 255, qc = t >> 8;
        const float* wob = Wout + (size_t)(qc * 64) * DG + c;
        const float* rs = &row_s[qc * 64];
        float a0 = 0.f, a1 = 0.f;
        #pragma unroll 8
        for (int i = 0; i < 64; i += 2) {
            a0 = fmaf(rs[i],     wob[(size_t)i * DG],       a0);
            a1 = fmaf(rs[i + 1], wob[(size_t)(i + 1) * DG], a1);
        }
        ps[qc][c] = a0 + a1;
    }
    __syncthreads();
    if (t < DG) {
        out[(size_t)bq * DG + t] = ps[0][t] + ps[1][t] + ps[2][t] + ps[3][t] + bout[t];
    }
}

extern "C" void kernel_launch(void* const* d_in, const int* in_sizes, int n_in,
                              void* d_out, int out_size, void* d_ws, size_t ws_size,
                              hipStream_t stream)
{
    const float* x       = (const float*)d_in[0];
    const float* bias    = (const float*)d_in[1];
    const float* g_gamma = (const float*)d_in[2];
    const float* g_beta  = (const float*)d_in[3];
    const float* b_gamma = (const float*)d_in[4];
    const float* b_beta  = (const float*)d_in[5];
    const float* Wq      = (const float*)d_in[6];
    const float* Wk      = (const float*)d_in[7];
    const float* Wv      = (const float*)d_in[8];
    const float* Wb      = (const float*)d_in[9];
    const float* Wg      = (const float*)d_in[10];
    const float* bg      = (const float*)d_in[11];
    const float* Wout    = (const float*)d_in[12];
    const float* bout    = (const float*)d_in[13];
    float* out = (float*)d_out;

    float* ws   = (float*)d_ws;
    float* q_ws = ws;                 // [1024, 256] each = 1 MB
    float* k_ws = ws + 262144;
    float* v_ws = ws + 2 * 262144;
    float* g_ws = ws + 3 * 262144;

    hipLaunchKernelGGL(prep_kernel, dim3(512), dim3(256), 0, stream,
                       x, g_gamma, g_beta, Wq, Wk, Wv, Wg, bg,
                       q_ws, k_ws, v_ws, g_ws);
    hipLaunchKernelGGL(attn_kernel, dim3(1024), dim3(1024), 0, stream,
                       bias, b_gamma, b_beta, Wb, Wout, bout,
                       q_ws, k_ws, v_ws, g_ws, out);
}

// Round 3
// 534.814 us; speedup vs baseline: 1.1048x; 1.0499x over previous
//
#include <hip/hip_runtime.h>
#include <math.h>

#define LSEQ 512
#define DG 256
#define DB 128
#define NH 8
#define HD 32
#define EPSV 1e-5f
#define LP2 516          // attn logits LDS row stride

typedef __attribute__((ext_vector_type(8))) short bf16x8;
typedef __attribute__((ext_vector_type(4))) float f32x4;

__device__ __forceinline__ unsigned short f2bf(float x) {
    unsigned int u = __float_as_uint(x);
    u += 0x7FFFu + ((u >> 16) & 1u);       // RNE
    return (unsigned short)(u >> 16);
}
__device__ __forceinline__ float bf2f(unsigned short h) {
    return __uint_as_float(((unsigned int)h) << 16);
}

// ---------------------------------------------------------------------------
// Kernel 1: layernorm(x) + Q/K/V/Gate projections. 256 blocks x 256 thr,
// 4 rows/block (weights re-read from L2 once per 4 rows).
// ---------------------------------------------------------------------------
__global__ __launch_bounds__(256) void prep_kernel(
    const float* __restrict__ x, const float* __restrict__ g_gamma,
    const float* __restrict__ g_beta, const float* __restrict__ Wq,
    const float* __restrict__ Wk, const float* __restrict__ Wv,
    const float* __restrict__ Wg, const float* __restrict__ bg,
    float* __restrict__ q_ws, float* __restrict__ k_ws,
    float* __restrict__ v_ws, float* __restrict__ g_ws)
{
    __shared__ float xs[4][DG];
    const int t = threadIdx.x;
    const int wave = t >> 6, lane = t & 63;
    const int row0 = blockIdx.x << 2;

    {   // one wave per row: layernorm over 256
        const int row = row0 + wave;
        const float4 xv = *(const float4*)(x + (size_t)row * DG + lane * 4);
        float s  = xv.x + xv.y + xv.z + xv.w;
        float ss = xv.x*xv.x + xv.y*xv.y + xv.z*xv.z + xv.w*xv.w;
        #pragma unroll
        for (int m = 32; m >= 1; m >>= 1) { s += __shfl_xor(s, m); ss += __shfl_xor(ss, m); }
        const float mean = s * (1.f / DG);
        const float rstd = rsqrtf(ss * (1.f / DG) - mean * mean + EPSV);
        const float4 gg = *(const float4*)(g_gamma + lane * 4);
        const float4 gb = *(const float4*)(g_beta + lane * 4);
        float4 xo;
        xo.x = (xv.x - mean) * rstd * gg.x + gb.x;
        xo.y = (xv.y - mean) * rstd * gg.y + gb.y;
        xo.z = (xv.z - mean) * rstd * gg.z + gb.z;
        xo.w = (xv.w - mean) * rstd * gg.w + gb.w;
        *(float4*)&xs[wave][lane * 4] = xo;
    }
    __syncthreads();

    float aq[4] = {0,0,0,0}, ak[4] = {0,0,0,0}, av[4] = {0,0,0,0}, ag[4] = {0,0,0,0};
    #pragma unroll 4
    for (int c = 0; c < DG; ++c) {
        const float wq = Wq[(size_t)c * DG + t];
        const float wk = Wk[(size_t)c * DG + t];
        const float wv = Wv[(size_t)c * DG + t];
        const float wg = Wg[(size_t)c * DG + t];
        #pragma unroll
        for (int r = 0; r < 4; ++r) {
            const float xr = xs[r][c];
            aq[r] = fmaf(xr, wq, aq[r]);
            ak[r] = fmaf(xr, wk, ak[r]);
            av[r] = fmaf(xr, wv, av[r]);
            ag[r] = fmaf(xr, wg, ag[r]);
        }
    }

    const float scal = 0.17677669529663687f;  // 1/sqrt(32)
    const float bgv = bg[t];
    #pragma unroll
    for (int r = 0; r < 4; ++r) {
        const size_t o = (size_t)(row0 + r) * DG + t;
        q_ws[o] = aq[r];
        k_ws[o] = ak[r] * scal;
        v_ws[o] = av[r];
        g_ws[o] = 1.f / (1.f + __expf(-(ag[r] + bgv)));
    }
}

// ---------------------------------------------------------------------------
// Kernel 2: bias layernorm + @Wb -> pair_ws [b*l, l, 8].  THE HBM streamer.
// 1024 blocks x 256 thr. Each wave independently: stage 16 bias rows via
// global_load_lds (async, dbuf, no barriers), MFMA(bf16 hi/lo) for row dots
// + ones-column row sums; ssq in fp32 VALU + 2 shuffles; bpermute routing.
// ---------------------------------------------------------------------------
__global__ __launch_bounds__(256) void pairb_kernel(
    const float* __restrict__ bias, const float* __restrict__ b_gamma,
    const float* __restrict__ b_beta, const float* __restrict__ Wb,
    float* __restrict__ pair_ws)
{
    __shared__ float lds[4 * 2 * 2048];      // 64 KB: [wave][buf][16 rows*128]
    const int t = threadIdx.x;
    const int w = t >> 6, l = t & 63;
    const int n = l & 15, quad = l >> 4;
    const int bq = blockIdx.x;

    // B-fragments (constant across all tiles): gw = gamma*Wb, split hi/lo.
    // col n==8 of gwhi = 1.0 -> MFMA also produces row sums in acc at n=8.
    bf16x8 gwhi[4], gwlo[4];
    float S1 = 0.f, S0 = 0.f;
    #pragma unroll
    for (int ks = 0; ks < 4; ++ks) {
        #pragma unroll
        for (int j = 0; j < 8; ++j) {
            const int c = ks * 32 + quad * 8 + j;
            const float wb = (n < 8) ? Wb[c * 8 + n] : 0.f;
            const float wv = b_gamma[c] * wb;
            S1 += wv;
            S0 += b_beta[c] * wb;
            unsigned short hi = f2bf(wv);
            unsigned short lo = f2bf(wv - bf2f(hi));
            if (n == 8) { hi = 0x3F80; lo = 0; }   // ones column
            gwhi[ks][j] = (short)hi;
            gwlo[ks][j] = (short)lo;
        }
    }
    S1 += __shfl_xor(S1, 16); S1 += __shfl_xor(S1, 32);
    S0 += __shfl_xor(S0, 16); S0 += __shfl_xor(S0, 32);

    float* myl = lds + w * 4096;                       // my 2 buffers
    const size_t rowbase = (size_t)bq * LSEQ + w * 16; // this wave's rows

    auto stage = [&](int tt, int buf) {
        const float* src = bias + (rowbase + (size_t)tt * 64) * DB;
        float* dst = myl + buf * 2048;
        #pragma unroll
        for (int i = 0; i < 8; ++i) {
            __builtin_amdgcn_global_load_lds(
                (const __attribute__((address_space(1))) void*)(src + i * 256 + l * 4),
                (__attribute__((address_space(3))) void*)(dst + i * 256 + l * 4),
                16, 0, 0);
        }
    };

    auto compute = [&](int tt, int buf) {
        const float* d = myl + buf * 2048 + n * 128 + quad * 8;
        f32x4 acc = {0.f, 0.f, 0.f, 0.f};
        float ssq = 0.f;
        #pragma unroll
        for (int ks = 0; ks < 4; ++ks) {
            const float4 x0 = *(const float4*)(d + ks * 32);
            const float4 x1 = *(const float4*)(d + ks * 32 + 4);
            ssq = fmaf(x0.x,x0.x, fmaf(x0.y,x0.y, fmaf(x0.z,x0.z, fmaf(x0.w,x0.w, ssq))));
            ssq = fmaf(x1.x,x1.x, fmaf(x1.y,x1.y, fmaf(x1.z,x1.z, fmaf(x1.w,x1.w, ssq))));
            const float xsv[8] = {x0.x,x0.y,x0.z,x0.w,x1.x,x1.y,x1.z,x1.w};
            bf16x8 ahi, alo;
            #pragma unroll
            for (int j = 0; j < 8; ++j) {
                const unsigned short hi = f2bf(xsv[j]);
                ahi[j] = (short)hi;
                alo[j] = (short)f2bf(xsv[j] - bf2f(hi));
            }
            acc = __builtin_amdgcn_mfma_f32_16x16x32_bf16(ahi, gwhi[ks], acc, 0, 0, 0);
            acc = __builtin_amdgcn_mfma_f32_16x16x32_bf16(alo, gwhi[ks], acc, 0, 0, 0);
            acc = __builtin_amdgcn_mfma_f32_16x16x32_bf16(ahi, gwlo[ks], acc, 0, 0, 0);
        }
        ssq += __shfl_xor(ssq, 16);
        ssq += __shfl_xor(ssq, 32);
        // D layout: row=(quad*4+reg), col=n. Row sums live at lane quad*16+8.
        float* pout = pair_ws + (rowbase + (size_t)tt * 64 + quad * 4) * NH + n;
        #pragma unroll
        for (int reg = 0; reg < 4; ++reg) {
            const float sumr = __uint_as_float((unsigned)__builtin_amdgcn_ds_bpermute(
                (quad * 16 + 8) * 4, (int)__float_as_uint(acc[reg])));
            const float ssqr = __uint_as_float((unsigned)__builtin_amdgcn_ds_bpermute(
                (quad * 4 + reg) * 4, (int)__float_as_uint(ssq)));
            const float mean = sumr * (1.f / DB);
            const float var  = ssqr * (1.f / DB) - mean * mean;
            const float rstd = rsqrtf(var + EPSV);
            const float p = rstd * (acc[reg] - mean * S1) + S0;
            if (n < NH) pout[reg * NH] = p;
        }
    };

    stage(0, 0);
    stage(1, 1);
    asm volatile("s_waitcnt vmcnt(8)" ::: "memory");
    compute(0, 0);
    for (int tt = 1; tt < 7; ++tt) {
        stage(tt + 1, (tt + 1) & 1);
        asm volatile("s_waitcnt vmcnt(12)" ::: "memory");   // 8 new loads + 4 stores
        compute(tt, tt & 1);
    }
    asm volatile("s_waitcnt vmcnt(4)" ::: "memory");
    compute(7, 1);
}

// ---------------------------------------------------------------------------
// Kernel 3: attention. 512 blocks (2 q-rows each) x 512 thr.
// logits(+pair) in LDS -> softmax -> @v -> gate -> @Wout.
// ---------------------------------------------------------------------------
__global__ __launch_bounds__(512) void attn_kernel(
    const float* __restrict__ pair_ws, const float* __restrict__ Wout,
    const float* __restrict__ bout, const float* __restrict__ q_ws,
    const float* __restrict__ k_ws, const float* __restrict__ v_ws,
    const float* __restrict__ g_ws, float* __restrict__ out)
{
    __shared__ float lg[2 * NH * LP2];     // 33 KB logits [q][h][k]
    __shared__ float q_s[2 * DG];
    __shared__ float ps[4 * 2 * 64 * 4];   // PV partials [s][q][c4]f4, 8 KB
    __shared__ float row_s[2 * DG];
    __shared__ float rden[16];

    const int t = threadIdx.x;
    const int b = blockIdx.x >> 8;
    const int q0 = (blockIdx.x & 255) * 2;

    // ---- Phase 0: stage pair -> lg (transposed), q rows ----
    {
        const float* pbase = pair_ws + ((size_t)(b * LSEQ + q0)) * LSEQ * NH;
        #pragma unroll
        for (int r = 0; r < 4; ++r) {
            const int f = r * 512 + t;            // float4 index in 2 q slices
            const float4 pv = *(const float4*)(pbase + (size_t)f * 4);
            const int q = f >> 10;
            const int o = (f * 4) & 4095;
            const int k = o >> 3, hb = o & 7;     // hb in {0,4}
            float* dst = lg + (q * NH + hb) * LP2 + k;
            dst[0] = pv.x; dst[LP2] = pv.y; dst[2*LP2] = pv.z; dst[3*LP2] = pv.w;
        }
        q_s[t] = q_ws[((size_t)(b * LSEQ + q0)) * DG + t];
    }
    __syncthreads();

    // ---- Phase 1: lg += q . k  (thread = (h, kk), 8 k each, 2 q inner) ----
    {
        const int h = t >> 6, kk = t & 63;
        const float* kb = k_ws + ((size_t)(b * LSEQ)) * DG + h * HD;
        const float* qp0 = q_s + h * HD;
        const float* qp1 = q_s + DG + h * HD;
        for (int j = 0; j < 8; ++j) {
            const int k = kk + j * 64;
            const float* kr = kb + (size_t)k * DG;
            float a0 = 0.f, a1 = 0.f;
            #pragma unroll
            for (int c = 0; c < 8; ++c) {
                const float4 kv = *(const float4*)(kr + c * 4);
                const float4 qa = *(const float4*)(qp0 + c * 4);
                const float4 qb = *(const float4*)(qp1 + c * 4);
                a0 = fmaf(kv.x, qa.x, fmaf(kv.y, qa.y, fmaf(kv.z, qa.z, fmaf(kv.w, qa.w, a0))));
                a1 = fmaf(kv.x, qb.x, fmaf(kv.y, qb.y, fmaf(kv.z, qb.z, fmaf(kv.w, qb.w, a1))));
            }
            lg[(0 * NH + h) * LP2 + k] += a0;
            lg[(1 * NH + h) * LP2 + k] += a1;
        }
    }
    __syncthreads();

    // ---- Phase 2: softmax over k per (q,h): 32 lanes per combo ----
    {
        const int qh = t >> 5, l32 = t & 31;
        float* lrow = lg + qh * LP2;
        float mx = -1e30f;
        #pragma unroll
        for (int i = 0; i < 16; ++i) mx = fmaxf(mx, lrow[l32 + i * 32]);
        #pragma unroll
        for (int m = 16; m >= 1; m >>= 1) mx = fmaxf(mx, __shfl_xor(mx, m));
        float s = 0.f;
        #pragma unroll
        for (int i = 0; i < 16; ++i) {
            const int k = l32 + i * 32;
            const float e = __expf(lrow[k] - mx);
            lrow[k] = e;
            s += e;
        }
        #pragma unroll
        for (int m = 16; m >= 1; m >>= 1) s += __shfl_xor(s, m);
        if (l32 == 0) rden[qh] = 1.f / s;
    }
    __syncthreads();

    // ---- Phase 3: PV, k split 4 ways ----
    {
        const int q = t >> 8, s4 = (t >> 6) & 3, c4 = t & 63;
        const int h = c4 >> 3;
        const float* vb = v_ws + ((size_t)(b * LSEQ + s4 * 128)) * DG + c4 * 4;
        const float* prow = lg + (q * NH + h) * LP2 + s4 * 128;
        float4 a = {0.f, 0.f, 0.f, 0.f};
        #pragma unroll 4
        for (int i = 0; i < 128; ++i) {
            const float p = prow[i];
            const float4 vv = *(const float4*)(vb + (size_t)i * DG);
            a.x = fmaf(p, vv.x, a.x);
            a.y = fmaf(p, vv.y, a.y);
            a.z = fmaf(p, vv.z, a.z);
            a.w = fmaf(p, vv.w, a.w);
        }
        *(float4*)&ps[((s4 * 2 + q) * 64 + c4) * 4] = a;
    }
    __syncthreads();
    if (t < 128) {
        const int q = t >> 6, c4 = t & 63, h = c4 >> 3;
        float4 a = *(const float4*)&ps[((0 * 2 + q) * 64 + c4) * 4];
        #pragma unroll
        for (int s4 = 1; s4 < 4; ++s4) {
            const float4 p4 = *(const float4*)&ps[((s4 * 2 + q) * 64 + c4) * 4];
            a.x += p4.x; a.y += p4.y; a.z += p4.z; a.w += p4.w;
        }
        const float sc = rden[q * NH + h];
        const float4 g4 = *(const float4*)(g_ws + ((size_t)(b * LSEQ + q0 + q)) * DG + c4 * 4);
        float* rs = row_s + q * DG + c4 * 4;
        rs[0] = a.x * sc * g4.x;
        rs[1] = a.y * sc * g4.y;
        rs[2] = a.z * sc * g4.z;
        rs[3] = a.w * sc * g4.w;
    }
    __syncthreads();

    // ---- Phase 4: row_s @ Wout + bout ----
    {
        const int q = t >> 8, co = t & 255;
        const float* rs = row_s + q * DG;
        const float* wo = Wout + co;
        float a = 0.f;
        #pragma unroll 4
        for (int c = 0; c < DG; ++c)
            a = fmaf(rs[c], wo[(size_t)c * DG], a);
        out[((size_t)(b * LSEQ + q0 + q)) * DG + co] = a + bout[co];
    }
}

extern "C" void kernel_launch(void* const* d_in, const int* in_sizes, int n_in,
                              void* d_out, int out_size, void* d_ws, size_t ws_size,
                              hipStream_t stream)
{
    const float* x       = (const float*)d_in[0];
    const float* bias    = (const float*)d_in[1];
    const float* g_gamma = (const float*)d_in[2];
    const float* g_beta  = (const float*)d_in[3];
    const float* b_gamma = (const float*)d_in[4];
    const float* b_beta  = (const float*)d_in[5];
    const float* Wq      = (const float*)d_in[6];
    const float* Wk      = (const float*)d_in[7];
    const float* Wv      = (const float*)d_in[8];
    const float* Wb      = (const float*)d_in[9];
    const float* Wg      = (const float*)d_in[10];
    const float* bg      = (const float*)d_in[11];
    const float* Wout    = (const float*)d_in[12];
    const float* bout    = (const float*)d_in[13];
    float* out = (float*)d_out;

    float* ws      = (float*)d_ws;
    float* q_ws    = ws;                    // 1 MB each
    float* k_ws    = ws + 262144;
    float* v_ws    = ws + 2 * 262144;
    float* g_ws    = ws + 3 * 262144;
    float* pair_ws = ws + 4 * 262144;       // [1024*512*8] = 16 MB

    hipLaunchKernelGGL(prep_kernel, dim3(256), dim3(256), 0, stream,
                       x, g_gamma, g_beta, Wq, Wk, Wv, Wg, bg,
                       q_ws, k_ws, v_ws, g_ws);
    hipLaunchKernelGGL(pairb_kernel, dim3(1024), dim3(256), 0, stream,
                       bias, b_gamma, b_beta, Wb, pair_ws);
    hipLaunchKernelGGL(attn_kernel, dim3(512), dim3(512), 0, stream,
                       pair_ws, Wout, bout, q_ws, k_ws, v_ws, g_ws, out);
}